// Round 1
// baseline (944.126 us; speedup 1.0000x reference)
//
#include <hip/hip_runtime.h>
#include <cstddef>

#define DEVINL __device__ __forceinline__

typedef float f32x4 __attribute__((ext_vector_type(4)));
typedef __bf16 bf16x8 __attribute__((ext_vector_type(8)));

DEVINL unsigned short f2bf(float f) {
  union { float f; unsigned int u; } v; v.f = f;
  unsigned int u = v.u;
  unsigned int r = (u + 0x7fffu + ((u >> 16) & 1u)) >> 16;
  return (unsigned short)r;
}
DEVINL float bf2f(unsigned short s) {
  union { unsigned int u; float f; } v; v.u = ((unsigned int)s) << 16;
  return v.f;
}
DEVINL uint4 pack8(const unsigned short o[8]) {
  uint4 r;
  r.x = (unsigned int)o[0] | ((unsigned int)o[1] << 16);
  r.y = (unsigned int)o[2] | ((unsigned int)o[3] << 16);
  r.z = (unsigned int)o[4] | ((unsigned int)o[5] << 16);
  r.w = (unsigned int)o[6] | ((unsigned int)o[7] << 16);
  return r;
}
DEVINL void gload16(const void* g, void* l) {
  __builtin_amdgcn_global_load_lds(
      (__attribute__((address_space(1))) void*)g,
      (__attribute__((address_space(3))) void*)l, 16, 0, 0);
}

// ---------------- fp32 -> bf16 convert ----------------
__global__ __launch_bounds__(256) void k_cvt(const float* __restrict__ in,
                                             unsigned short* __restrict__ out, int n4) {
  int i = blockIdx.x * 256 + threadIdx.x;
  if (i >= n4) return;
  float4 v = ((const float4*)in)[i];
  ushort4 o;
  o.x = f2bf(v.x); o.y = f2bf(v.y); o.z = f2bf(v.z); o.w = f2bf(v.w);
  ((ushort4*)out)[i] = o;
}

// ---------------- GEMM: C[m][n] = sum_k A[m][k] * Bt[n][k] ----------------
// 128x128 tile, BK=32, 256 threads (4 waves, 2x2), global_load_lds width-16.
template <int OUT_BF16>
__global__ __launch_bounds__(256) void k_gemm_bt(const unsigned short* __restrict__ A,
                                                 const unsigned short* __restrict__ Bt,
                                                 void* __restrict__ Cout,
                                                 int M, int N, int K) {
  __shared__ __align__(16) unsigned short As[128 * 32];
  __shared__ __align__(16) unsigned short Bs[128 * 32];
  const int t = threadIdx.x;
  const int lane = t & 63, wv = t >> 6;
  const int wr = wv >> 1, wc = wv & 1;
  const int row0 = blockIdx.y * 128, col0 = blockIdx.x * 128;
  const int fr = lane & 15;
  const int kh = (lane >> 4) * 8;
  f32x4 acc[4][4];
#pragma unroll
  for (int m = 0; m < 4; ++m)
#pragma unroll
    for (int n = 0; n < 4; ++n) acc[m][n] = f32x4{0.f, 0.f, 0.f, 0.f};

  const int off0 = wv * 1024 + lane * 16;
  for (int k0 = 0; k0 < K; k0 += 32) {
#pragma unroll
    for (int it = 0; it < 2; ++it) {
      const int off = off0 + it * 4096;   // byte offset in 8KB tile
      const int r = off >> 6;             // 64 B per row (32 bf16)
      const int cb = off & 63;
      gload16(A + (size_t)(row0 + r) * K + k0 + (cb >> 1),
              (char*)As + wv * 1024 + it * 4096);
      gload16(Bt + (size_t)(col0 + r) * K + k0 + (cb >> 1),
              (char*)Bs + wv * 1024 + it * 4096);
    }
    __syncthreads();
    bf16x8 af[4], bfr[4];
#pragma unroll
    for (int m = 0; m < 4; ++m)
      af[m] = *(const bf16x8*)&As[(wr * 64 + m * 16 + fr) * 32 + kh];
#pragma unroll
    for (int n = 0; n < 4; ++n)
      bfr[n] = *(const bf16x8*)&Bs[(wc * 64 + n * 16 + fr) * 32 + kh];
#pragma unroll
    for (int m = 0; m < 4; ++m)
#pragma unroll
      for (int n = 0; n < 4; ++n)
        acc[m][n] = __builtin_amdgcn_mfma_f32_16x16x32_bf16(af[m], bfr[n], acc[m][n], 0, 0, 0);
    __syncthreads();
  }
  const int rsub = (lane >> 4) * 4;
#pragma unroll
  for (int m = 0; m < 4; ++m)
#pragma unroll
    for (int n = 0; n < 4; ++n)
#pragma unroll
      for (int r = 0; r < 4; ++r) {
        const size_t row = (size_t)row0 + wr * 64 + m * 16 + rsub + r;
        const size_t col = (size_t)col0 + wc * 64 + n * 16 + fr;
        if (OUT_BF16)
          ((unsigned short*)Cout)[row * N + col] = f2bf(acc[m][n][r]);
        else
          ((float*)Cout)[row * N + col] = acc[m][n][r];
      }
}

// ---------------- RoPE + head split (qkv bf16 -> Q/K/V bf16) ----------------
// qkv: [4096][6144]; o = (g*6 + slot)*128 + d. slot 0..3 -> Q (scaled), 4 -> K, 5 -> V.
__global__ __launch_bounds__(256) void k_rope(const unsigned short* __restrict__ qkv,
                                              const float* __restrict__ fcos,
                                              const float* __restrict__ fsin,
                                              unsigned short* __restrict__ Qb,
                                              unsigned short* __restrict__ Kb,
                                              unsigned short* __restrict__ Vb) {
  const int idx = blockIdx.x * 256 + threadIdx.x;  // < 4096*768
  if (idx >= 4096 * 768) return;
  const int bt = idx / 768;
  const int oc = idx - bt * 768;
  const int o0 = oc * 8;
  const int g = o0 / 768;
  const int rem = o0 - g * 768;
  const int slot = rem >> 7;
  const int d0 = rem & 127;
  const int b = bt >> 10, tt = bt & 1023;

  uint4 raw = *(const uint4*)&qkv[(size_t)bt * 6144 + o0];
  unsigned short us[8] = {
      (unsigned short)(raw.x & 0xffff), (unsigned short)(raw.x >> 16),
      (unsigned short)(raw.y & 0xffff), (unsigned short)(raw.y >> 16),
      (unsigned short)(raw.z & 0xffff), (unsigned short)(raw.z >> 16),
      (unsigned short)(raw.w & 0xffff), (unsigned short)(raw.w >> 16)};

  if (slot == 5) {
    *(uint4*)&Vb[((size_t)(b * 8 + g) * 1024 + tt) * 128 + d0] = pack8(us);
    return;
  }
  float4 c = *(const float4*)&fcos[tt * 64 + (d0 >> 1)];
  float4 s = *(const float4*)&fsin[tt * 64 + (d0 >> 1)];
  const float sc = (slot < 4) ? 0.08838834764831845f : 1.0f;  // 1/sqrt(128) folded into Q
  float cj[4] = {c.x, c.y, c.z, c.w};
  float sj[4] = {s.x, s.y, s.z, s.w};
  unsigned short os[8];
#pragma unroll
  for (int j = 0; j < 4; ++j) {
    float x0 = bf2f(us[2 * j]), x1 = bf2f(us[2 * j + 1]);
    os[2 * j] = f2bf((x0 * cj[j] - x1 * sj[j]) * sc);
    os[2 * j + 1] = f2bf((x0 * sj[j] + x1 * cj[j]) * sc);
  }
  if (slot < 4) {
    const int h = g * 4 + slot;
    *(uint4*)&Qb[((size_t)(b * 32 + h) * 1024 + tt) * 128 + d0] = pack8(os);
  } else {
    *(uint4*)&Kb[((size_t)(b * 8 + g) * 1024 + tt) * 128 + d0] = pack8(os);
  }
}

// ---------------- causal GQA flash attention ----------------
// block = (q-tile of 64, (b,h)); 4 waves x 16 q-rows; KV tiles of 32.
__global__ __launch_bounds__(256) void k_attn(const unsigned short* __restrict__ Qb,
                                              const unsigned short* __restrict__ Kb,
                                              const unsigned short* __restrict__ Vb,
                                              unsigned short* __restrict__ AO) {
  __shared__ __align__(16) unsigned short Ks[32 * 128];   // XOR-swizzled within rows
  __shared__ __align__(16) unsigned short Vt[128 * 32];   // V transposed [d][kv]
  __shared__ __align__(16) unsigned short Ps[4 * 16 * 32];
  const int t = threadIdx.x, lane = t & 63, wv = t >> 6;
  const int bh = blockIdx.y;
  const int b = bh >> 5, h = bh & 31, g = h >> 2;
  const int q0 = blockIdx.x * 64;
  const int fr = lane & 15, kq = lane >> 4;
  const size_t kvbase = (size_t)(b * 8 + g) * (1024 * 128);

  bf16x8 qf[4];
  {
    const unsigned short* Qp = Qb + ((size_t)(b * 32 + h) * 1024 + q0 + wv * 16 + fr) * 128;
#pragma unroll
    for (int ks = 0; ks < 4; ++ks) qf[ks] = *(const bf16x8*)&Qp[ks * 32 + kq * 8];
  }
  float mrow[4] = {-1e30f, -1e30f, -1e30f, -1e30f};
  float lrow[4] = {0.f, 0.f, 0.f, 0.f};
  f32x4 of[8];
#pragma unroll
  for (int n = 0; n < 8; ++n) of[n] = f32x4{0.f, 0.f, 0.f, 0.f};

  const int ktmax = (q0 + 63) >> 5;  // inclusive
  for (int kt = 0; kt <= ktmax; ++kt) {
    const int kv0 = kt * 32;
    // stage K: LDS linear [32][256B], global source pre-swizzled (involution)
#pragma unroll
    for (int it = 0; it < 2; ++it) {
      const int off = wv * 1024 + it * 4096 + lane * 16;
      const int r = off >> 8, cb = off & 255;
      const int scb = cb ^ ((r & 7) << 4);
      gload16(Kb + kvbase + (size_t)(kv0 + r) * 128 + (scb >> 1),
              (char*)Ks + wv * 1024 + it * 4096);
    }
    // stage V transposed via registers
#pragma unroll
    for (int it = 0; it < 2; ++it) {
      const int kv = it * 16 + (t >> 4);
      const int d0 = (t & 15) * 8;
      uint4 raw = *(const uint4*)&Vb[kvbase + (size_t)(kv0 + kv) * 128 + d0];
      const unsigned short vs[8] = {
          (unsigned short)(raw.x & 0xffff), (unsigned short)(raw.x >> 16),
          (unsigned short)(raw.y & 0xffff), (unsigned short)(raw.y >> 16),
          (unsigned short)(raw.z & 0xffff), (unsigned short)(raw.z >> 16),
          (unsigned short)(raw.w & 0xffff), (unsigned short)(raw.w >> 16)};
#pragma unroll
      for (int j = 0; j < 8; ++j) Vt[(d0 + j) * 32 + kv] = vs[j];
    }
    __syncthreads();

    // S = Q * K^T  (16x32 per wave)
    f32x4 sacc[2];
    sacc[0] = f32x4{0.f, 0.f, 0.f, 0.f};
    sacc[1] = f32x4{0.f, 0.f, 0.f, 0.f};
#pragma unroll
    for (int n = 0; n < 2; ++n) {
      const int r = fr + n * 16;
      const int sw = (r & 7) << 4;
#pragma unroll
      for (int ks = 0; ks < 4; ++ks) {
        const int db = ks * 64 + kq * 16;
        bf16x8 kf = *(const bf16x8*)((const char*)Ks + r * 256 + (db ^ sw));
        sacc[n] = __builtin_amdgcn_mfma_f32_16x16x32_bf16(qf[ks], kf, sacc[n], 0, 0, 0);
      }
    }
    // online softmax (rows live in C-layout: row = kq*4+rg, col = fr + 16n)
#pragma unroll
    for (int rg = 0; rg < 4; ++rg) {
      const int qrow = q0 + wv * 16 + kq * 4 + rg;
      float s0 = sacc[0][rg], s1 = sacc[1][rg];
      if (kv0 + fr > qrow) s0 = -1e30f;
      if (kv0 + 16 + fr > qrow) s1 = -1e30f;
      float mx = fmaxf(s0, s1);
#pragma unroll
      for (int o = 1; o < 16; o <<= 1) mx = fmaxf(mx, __shfl_xor(mx, o));
      const float mnew = fmaxf(mrow[rg], mx);
      const float p0 = __expf(s0 - mnew), p1 = __expf(s1 - mnew);
      float sum = p0 + p1;
#pragma unroll
      for (int o = 1; o < 16; o <<= 1) sum += __shfl_xor(sum, o);
      const float fac = __expf(mrow[rg] - mnew);
      lrow[rg] = lrow[rg] * fac + sum;
      mrow[rg] = mnew;
#pragma unroll
      for (int n = 0; n < 8; ++n) of[n][rg] *= fac;
      Ps[wv * 512 + (kq * 4 + rg) * 32 + fr] = f2bf(p0);
      Ps[wv * 512 + (kq * 4 + rg) * 32 + 16 + fr] = f2bf(p1);
    }
    asm volatile("s_waitcnt lgkmcnt(0)" ::: "memory");
    __builtin_amdgcn_sched_barrier(0);
    // PV: A = P (16x32), B = Vt [d][kv]
    bf16x8 pa = *(const bf16x8*)&Ps[wv * 512 + fr * 32 + kq * 8];
#pragma unroll
    for (int n = 0; n < 8; ++n) {
      bf16x8 vf = *(const bf16x8*)&Vt[(n * 16 + fr) * 32 + kq * 8];
      of[n] = __builtin_amdgcn_mfma_f32_16x16x32_bf16(pa, vf, of[n], 0, 0, 0);
    }
    __syncthreads();
  }
  float inv[4];
#pragma unroll
  for (int rg = 0; rg < 4; ++rg) inv[rg] = 1.0f / lrow[rg];
#pragma unroll
  for (int n = 0; n < 8; ++n)
#pragma unroll
    for (int rg = 0; rg < 4; ++rg) {
      const size_t row = (size_t)b * 1024 + q0 + wv * 16 + kq * 4 + rg;
      const size_t col = (size_t)h * 128 + n * 16 + fr;
      AO[row * 4096 + col] = f2bf(of[n][rg] * inv[rg]);
    }
}

// ---------------- launch ----------------
extern "C" void kernel_launch(void* const* d_in, const int* in_sizes, int n_in,
                              void* d_out, int out_size, void* d_ws, size_t ws_size,
                              hipStream_t stream) {
  const float* x = (const float*)d_in[0];
  const float* w_qkv = (const float*)d_in[1];
  const float* w_proj = (const float*)d_in[2];
  const float* fcos = (const float*)d_in[3];
  const float* fsin = (const float*)d_in[4];
  float* out = (float*)d_out;

  char* ws = (char*)d_ws;
  unsigned short* XB    = (unsigned short*)(ws + 0);          // 33.5 MB  x bf16
  unsigned short* WQKVB = (unsigned short*)(ws + 33554432);   // 50.3 MB  w_qkv bf16
  unsigned short* QKVB  = (unsigned short*)(ws + 83886080);   // 50.3 MB  qkv bf16
  unsigned short* QB    = (unsigned short*)(ws + 134217728);  // 33.5 MB
  unsigned short* KB    = (unsigned short*)(ws + 167772160);  // 8.4 MB
  unsigned short* VB    = (unsigned short*)(ws + 176160768);  // 8.4 MB  (end 184.5 MB)
  unsigned short* WPROJB = XB;    // reuse x slot after GEMM1
  unsigned short* AOB    = QKVB;  // reuse qkv slot after RoPE

  k_cvt<<<16384, 256, 0, stream>>>(x, XB, 4194304);
  k_cvt<<<24576, 256, 0, stream>>>(w_qkv, WQKVB, 6291456);
  k_gemm_bt<1><<<dim3(48, 32), 256, 0, stream>>>(XB, WQKVB, QKVB, 4096, 6144, 4096);
  k_cvt<<<16384, 256, 0, stream>>>(w_proj, WPROJB, 4194304);
  k_rope<<<12288, 256, 0, stream>>>(QKVB, fcos, fsin, QB, KB, VB);
  k_attn<<<dim3(16, 128), 256, 0, stream>>>(QB, KB, VB, AOB);
  k_gemm_bt<0><<<dim3(32, 32), 256, 0, stream>>>(AOB, WPROJB, out, 4096, 4096, 4096);
}

// Round 2
// 709.405 us; speedup vs baseline: 1.3309x; 1.3309x over previous
//
#include <hip/hip_runtime.h>
#include <cstddef>

#define DEVINL __device__ __forceinline__

typedef float f32x4 __attribute__((ext_vector_type(4)));
typedef __bf16 bf16x8 __attribute__((ext_vector_type(8)));

DEVINL unsigned short f2bf(float f) {
  union { float f; unsigned int u; } v; v.f = f;
  unsigned int u = v.u;
  unsigned int r = (u + 0x7fffu + ((u >> 16) & 1u)) >> 16;
  return (unsigned short)r;
}
DEVINL float bf2f(unsigned short s) {
  union { unsigned int u; float f; } v; v.u = ((unsigned int)s) << 16;
  return v.f;
}
DEVINL uint4 pack8(const unsigned short o[8]) {
  uint4 r;
  r.x = (unsigned int)o[0] | ((unsigned int)o[1] << 16);
  r.y = (unsigned int)o[2] | ((unsigned int)o[3] << 16);
  r.z = (unsigned int)o[4] | ((unsigned int)o[5] << 16);
  r.w = (unsigned int)o[6] | ((unsigned int)o[7] << 16);
  return r;
}
DEVINL void gload16(const void* g, void* l) {
  __builtin_amdgcn_global_load_lds(
      (__attribute__((address_space(1))) void*)g,
      (__attribute__((address_space(3))) void*)l, 16, 0, 0);
}

// ---------------- fp32 -> bf16 convert ----------------
__global__ __launch_bounds__(256) void k_cvt(const float* __restrict__ in,
                                             unsigned short* __restrict__ out, int n4) {
  int i = blockIdx.x * 256 + threadIdx.x;
  if (i >= n4) return;
  float4 v = ((const float4*)in)[i];
  ushort4 o;
  o.x = f2bf(v.x); o.y = f2bf(v.y); o.z = f2bf(v.z); o.w = f2bf(v.w);
  ((ushort4*)out)[i] = o;
}

// ---------------- GEMM: C[m][n] = sum_k A[m][k] * Bt[n][k] ----------------
template <int OUT_BF16>
__global__ __launch_bounds__(256) void k_gemm_bt(const unsigned short* __restrict__ A,
                                                 const unsigned short* __restrict__ Bt,
                                                 void* __restrict__ Cout,
                                                 int M, int N, int K) {
  __shared__ __align__(16) unsigned short As[128 * 32];
  __shared__ __align__(16) unsigned short Bs[128 * 32];
  const int t = threadIdx.x;
  const int lane = t & 63, wv = t >> 6;
  const int wr = wv >> 1, wc = wv & 1;
  const int row0 = blockIdx.y * 128, col0 = blockIdx.x * 128;
  const int fr = lane & 15;
  const int kh = (lane >> 4) * 8;
  f32x4 acc[4][4];
#pragma unroll
  for (int m = 0; m < 4; ++m)
#pragma unroll
    for (int n = 0; n < 4; ++n) acc[m][n] = f32x4{0.f, 0.f, 0.f, 0.f};

  const int off0 = wv * 1024 + lane * 16;
  for (int k0 = 0; k0 < K; k0 += 32) {
#pragma unroll
    for (int it = 0; it < 2; ++it) {
      const int off = off0 + it * 4096;   // byte offset in 8KB tile
      const int r = off >> 6;             // 64 B per row (32 bf16)
      const int cb = off & 63;
      gload16(A + (size_t)(row0 + r) * K + k0 + (cb >> 1),
              (char*)As + wv * 1024 + it * 4096);
      gload16(Bt + (size_t)(col0 + r) * K + k0 + (cb >> 1),
              (char*)Bs + wv * 1024 + it * 4096);
    }
    __syncthreads();
    bf16x8 af[4], bfr[4];
#pragma unroll
    for (int m = 0; m < 4; ++m)
      af[m] = *(const bf16x8*)&As[(wr * 64 + m * 16 + fr) * 32 + kh];
#pragma unroll
    for (int n = 0; n < 4; ++n)
      bfr[n] = *(const bf16x8*)&Bs[(wc * 64 + n * 16 + fr) * 32 + kh];
#pragma unroll
    for (int m = 0; m < 4; ++m)
#pragma unroll
      for (int n = 0; n < 4; ++n)
        acc[m][n] = __builtin_amdgcn_mfma_f32_16x16x32_bf16(af[m], bfr[n], acc[m][n], 0, 0, 0);
    __syncthreads();
  }
  const int rsub = (lane >> 4) * 4;
#pragma unroll
  for (int m = 0; m < 4; ++m)
#pragma unroll
    for (int n = 0; n < 4; ++n)
#pragma unroll
      for (int r = 0; r < 4; ++r) {
        const size_t row = (size_t)row0 + wr * 64 + m * 16 + rsub + r;
        const size_t col = (size_t)col0 + wc * 64 + n * 16 + fr;
        if (OUT_BF16)
          ((unsigned short*)Cout)[row * N + col] = f2bf(acc[m][n][r]);
        else
          ((float*)Cout)[row * N + col] = acc[m][n][r];
      }
}

// ---------------- RoPE + head split (qkv bf16 -> Q/K bf16; V skipped) ------
__global__ __launch_bounds__(256) void k_rope(const unsigned short* __restrict__ qkv,
                                              const float* __restrict__ fcos,
                                              const float* __restrict__ fsin,
                                              unsigned short* __restrict__ Qb,
                                              unsigned short* __restrict__ Kb) {
  const int idx = blockIdx.x * 256 + threadIdx.x;  // < 4096*768
  if (idx >= 4096 * 768) return;
  const int bt = idx / 768;
  const int oc = idx - bt * 768;
  const int o0 = oc * 8;
  const int g = o0 / 768;
  const int rem = o0 - g * 768;
  const int slot = rem >> 7;
  const int d0 = rem & 127;
  if (slot == 5) return;  // V handled by k_vtrans
  const int b = bt >> 10, tt = bt & 1023;

  uint4 raw = *(const uint4*)&qkv[(size_t)bt * 6144 + o0];
  unsigned short us[8] = {
      (unsigned short)(raw.x & 0xffff), (unsigned short)(raw.x >> 16),
      (unsigned short)(raw.y & 0xffff), (unsigned short)(raw.y >> 16),
      (unsigned short)(raw.z & 0xffff), (unsigned short)(raw.z >> 16),
      (unsigned short)(raw.w & 0xffff), (unsigned short)(raw.w >> 16)};

  float4 c = *(const float4*)&fcos[tt * 64 + (d0 >> 1)];
  float4 s = *(const float4*)&fsin[tt * 64 + (d0 >> 1)];
  const float sc = (slot < 4) ? 0.08838834764831845f : 1.0f;  // 1/sqrt(128) folded into Q
  float cj[4] = {c.x, c.y, c.z, c.w};
  float sj[4] = {s.x, s.y, s.z, s.w};
  unsigned short os[8];
#pragma unroll
  for (int j = 0; j < 4; ++j) {
    float x0 = bf2f(us[2 * j]), x1 = bf2f(us[2 * j + 1]);
    os[2 * j] = f2bf((x0 * cj[j] - x1 * sj[j]) * sc);
    os[2 * j + 1] = f2bf((x0 * sj[j] + x1 * cj[j]) * sc);
  }
  if (slot < 4) {
    const int h = g * 4 + slot;
    *(uint4*)&Qb[((size_t)(b * 32 + h) * 1024 + tt) * 128 + d0] = pack8(os);
  } else {
    *(uint4*)&Kb[((size_t)(b * 8 + g) * 1024 + tt) * 128 + d0] = pack8(os);
  }
}

// ---------------- V transpose: QKVB -> VT[bg][d=128][t=1024] ----------------
// 8x8 u16 register transpose per thread via v_perm; tile 128t x 128d per block.
__global__ __launch_bounds__(256) void k_vtrans(const unsigned short* __restrict__ qkv,
                                                unsigned short* __restrict__ VT) {
  const int t = threadIdx.x;
  const int tt0 = blockIdx.x * 128;
  const int bg = blockIdx.y;
  const int b = bg >> 3, g = bg & 7;
  const int tj = t & 15;   // d-block (fast lane index -> coalesced reads)
  const int ti = t >> 4;   // t-block
  union U4 { uint4 v; unsigned int u[4]; };
  U4 in[8], out[8];
  const unsigned short* src =
      qkv + (size_t)(b * 1024 + tt0 + ti * 8) * 6144 + g * 768 + 640 + tj * 8;
#pragma unroll
  for (int r = 0; r < 8; ++r) in[r].v = *(const uint4*)(src + (size_t)r * 6144);
#pragma unroll
  for (int c = 0; c < 8; ++c) {
    const unsigned int sel = (c & 1) ? 0x07060302u : 0x05040100u;
    const int dw = c >> 1;
#pragma unroll
    for (int w = 0; w < 4; ++w)
      out[c].u[w] = __builtin_amdgcn_perm(in[2 * w + 1].u[dw], in[2 * w].u[dw], sel);
  }
  unsigned short* dst = VT + (size_t)bg * 131072 + (size_t)(tj * 8) * 1024 + tt0 + ti * 8;
#pragma unroll
  for (int c = 0; c < 8; ++c) *(uint4*)(dst + (size_t)c * 1024) = out[c].v;
}

// ---------------- causal GQA flash attention ----------------
// block = (q-tile 64, (b,h)); 4 waves x 16 q-rows; KV tiles of 64; all LDS swizzled.
__global__ __launch_bounds__(256) void k_attn(const unsigned short* __restrict__ Qb,
                                              const unsigned short* __restrict__ Kb,
                                              const unsigned short* __restrict__ VT,
                                              unsigned short* __restrict__ AO) {
  __shared__ __align__(16) unsigned short Ks[64 * 128];   // [kv][d], 256B rows, XOR-swz
  __shared__ __align__(16) unsigned short Vt[128 * 64];   // [d][kv], 128B rows, XOR-swz
  __shared__ __align__(16) unsigned short Ps[4 * 16 * 64]; // per-wave [q16][kv64], XOR-swz
  const int t = threadIdx.x, lane = t & 63, wv = t >> 6;
  const int bh = blockIdx.y;
  const int b = bh >> 5, h = bh & 31, g = h >> 2;
  const int qi = blockIdx.x;
  const int q0 = qi * 64;
  const int fr = lane & 15, kq = lane >> 4;
  const size_t kvbase = (size_t)(b * 8 + g) * (1024 * 128);
  const size_t vtbase = (size_t)(b * 8 + g) * (128 * 1024);

  bf16x8 qf[4];
  {
    const unsigned short* Qp = Qb + ((size_t)(b * 32 + h) * 1024 + q0 + wv * 16 + fr) * 128;
#pragma unroll
    for (int ks = 0; ks < 4; ++ks) qf[ks] = *(const bf16x8*)&Qp[ks * 32 + kq * 8];
  }
  float mrow[4] = {-1e30f, -1e30f, -1e30f, -1e30f};
  float lrow[4] = {0.f, 0.f, 0.f, 0.f};
  f32x4 of[8];
#pragma unroll
  for (int n = 0; n < 8; ++n) of[n] = f32x4{0.f, 0.f, 0.f, 0.f};

  for (int kt = 0; kt <= qi; ++kt) {
    const int kv0 = kt * 64;
    // stage K tile [64][128] and V^T tile [128][64], pre-swizzled global source
#pragma unroll
    for (int it = 0; it < 4; ++it) {
      const int off = it * 4096 + wv * 1024 + lane * 16;
      {
        const int r = off >> 8, cb = off & 255;
        const int scb = cb ^ ((r & 7) << 4);
        gload16(Kb + kvbase + (size_t)(kv0 + r) * 128 + (scb >> 1),
                (char*)Ks + it * 4096 + wv * 1024);
      }
      {
        const int rd = off >> 7, cb = off & 127;
        const int scb = cb ^ ((rd & 7) << 4);
        gload16(VT + vtbase + (size_t)rd * 1024 + kv0 + (scb >> 1),
                (char*)Vt + it * 4096 + wv * 1024);
      }
    }
    __syncthreads();

    // S = Q K^T : 16q x 64kv per wave
    f32x4 sacc[4];
#pragma unroll
    for (int n = 0; n < 4; ++n) sacc[n] = f32x4{0.f, 0.f, 0.f, 0.f};
#pragma unroll
    for (int n = 0; n < 4; ++n) {
      const int row = n * 16 + fr;
      const int sw = (row & 7) << 4;
#pragma unroll
      for (int ks = 0; ks < 4; ++ks) {
        bf16x8 kf = *(const bf16x8*)((const char*)Ks + row * 256 + ((ks * 64 + kq * 16) ^ sw));
        sacc[n] = __builtin_amdgcn_mfma_f32_16x16x32_bf16(qf[ks], kf, sacc[n], 0, 0, 0);
      }
    }

    // online softmax; rows: q = kq*4+rg, cols: kv = n*16+fr
#pragma unroll
    for (int rg = 0; rg < 4; ++rg) {
      const int qrow = q0 + wv * 16 + kq * 4 + rg;
      float s[4];
#pragma unroll
      for (int n = 0; n < 4; ++n) {
        s[n] = sacc[n][rg];
        if (kv0 + n * 16 + fr > qrow) s[n] = -1e30f;
      }
      float mx = fmaxf(fmaxf(s[0], s[1]), fmaxf(s[2], s[3]));
#pragma unroll
      for (int o = 1; o < 16; o <<= 1) mx = fmaxf(mx, __shfl_xor(mx, o));
      const float mnew = fmaxf(mrow[rg], mx);
      float p[4];
#pragma unroll
      for (int n = 0; n < 4; ++n) p[n] = __expf(s[n] - mnew);
      float sum = (p[0] + p[1]) + (p[2] + p[3]);
#pragma unroll
      for (int o = 1; o < 16; o <<= 1) sum += __shfl_xor(sum, o);
      const float fac = __expf(mrow[rg] - mnew);
      lrow[rg] = lrow[rg] * fac + sum;
      mrow[rg] = mnew;
#pragma unroll
      for (int n = 0; n < 8; ++n) of[n][rg] *= fac;
      const int q = kq * 4 + rg;
      const int swp = (q & 7) << 4;
#pragma unroll
      for (int n = 0; n < 4; ++n)
        *(unsigned short*)((char*)Ps + wv * 2048 + q * 128 + ((2 * (n * 16 + fr)) ^ swp)) =
            f2bf(p[n]);
    }

    // PV: O += P[16x64] * V^T  (per-wave Ps, no barrier needed)
    bf16x8 pa[2];
#pragma unroll
    for (int kk = 0; kk < 2; ++kk)
      pa[kk] = *(const bf16x8*)((const char*)Ps + wv * 2048 + fr * 128 +
                                ((kk * 64 + kq * 16) ^ ((fr & 7) << 4)));
#pragma unroll
    for (int n = 0; n < 8; ++n) {
      const int row = n * 16 + fr;
      const int sw = (row & 7) << 4;
#pragma unroll
      for (int kk = 0; kk < 2; ++kk) {
        bf16x8 vf = *(const bf16x8*)((const char*)Vt + row * 128 + ((kk * 64 + kq * 16) ^ sw));
        of[n] = __builtin_amdgcn_mfma_f32_16x16x32_bf16(pa[kk], vf, of[n], 0, 0, 0);
      }
    }
    __syncthreads();
  }

  float inv[4];
#pragma unroll
  for (int rg = 0; rg < 4; ++rg) inv[rg] = 1.0f / lrow[rg];
#pragma unroll
  for (int n = 0; n < 8; ++n)
#pragma unroll
    for (int rg = 0; rg < 4; ++rg) {
      const size_t row = (size_t)b * 1024 + q0 + wv * 16 + kq * 4 + rg;
      const size_t col = (size_t)h * 128 + n * 16 + fr;
      AO[row * 4096 + col] = f2bf(of[n][rg] * inv[rg]);
    }
}

// ---------------- launch ----------------
extern "C" void kernel_launch(void* const* d_in, const int* in_sizes, int n_in,
                              void* d_out, int out_size, void* d_ws, size_t ws_size,
                              hipStream_t stream) {
  const float* x = (const float*)d_in[0];
  const float* w_qkv = (const float*)d_in[1];
  const float* w_proj = (const float*)d_in[2];
  const float* fcos = (const float*)d_in[3];
  const float* fsin = (const float*)d_in[4];
  float* out = (float*)d_out;

  char* ws = (char*)d_ws;
  unsigned short* XB    = (unsigned short*)(ws + 0);          // x bf16
  unsigned short* WQKVB = (unsigned short*)(ws + 33554432);   // w_qkv bf16
  unsigned short* QKVB  = (unsigned short*)(ws + 83886080);   // qkv bf16
  unsigned short* QB    = (unsigned short*)(ws + 134217728);
  unsigned short* KB    = (unsigned short*)(ws + 167772160);
  unsigned short* VTB   = (unsigned short*)(ws + 176160768);  // V^T [bg][128][1024]
  unsigned short* WPROJB = XB;    // reuse x slot after GEMM1
  unsigned short* AOB    = QKVB;  // reuse qkv slot (V read via VTB)

  k_cvt<<<16384, 256, 0, stream>>>(x, XB, 4194304);
  k_cvt<<<24576, 256, 0, stream>>>(w_qkv, WQKVB, 6291456);
  k_gemm_bt<1><<<dim3(48, 32), 256, 0, stream>>>(XB, WQKVB, QKVB, 4096, 6144, 4096);
  k_cvt<<<16384, 256, 0, stream>>>(w_proj, WPROJB, 4194304);
  k_rope<<<12288, 256, 0, stream>>>(QKVB, fcos, fsin, QB, KB);
  k_vtrans<<<dim3(8, 32), 256, 0, stream>>>(QKVB, VTB);
  k_attn<<<dim3(16, 128), 256, 0, stream>>>(QB, KB, VTB, AOB);
  k_gemm_bt<0><<<dim3(32, 32), 256, 0, stream>>>(AOB, WPROJB, out, 4096, 4096, 4096);
}

// Round 3
// 698.769 us; speedup vs baseline: 1.3511x; 1.0152x over previous
//
#include <hip/hip_runtime.h>
#include <cstddef>

#define DEVINL __device__ __forceinline__

typedef float f32x4 __attribute__((ext_vector_type(4)));
typedef __bf16 bf16x8 __attribute__((ext_vector_type(8)));

DEVINL unsigned short f2bf(float f) {
  union { float f; unsigned int u; } v; v.f = f;
  unsigned int u = v.u;
  unsigned int r = (u + 0x7fffu + ((u >> 16) & 1u)) >> 16;
  return (unsigned short)r;
}
DEVINL float bf2f(unsigned short s) {
  union { unsigned int u; float f; } v; v.u = ((unsigned int)s) << 16;
  return v.f;
}
DEVINL uint4 pack8(const unsigned short o[8]) {
  uint4 r;
  r.x = (unsigned int)o[0] | ((unsigned int)o[1] << 16);
  r.y = (unsigned int)o[2] | ((unsigned int)o[3] << 16);
  r.z = (unsigned int)o[4] | ((unsigned int)o[5] << 16);
  r.w = (unsigned int)o[6] | ((unsigned int)o[7] << 16);
  return r;
}
DEVINL void gload16(const void* g, void* l) {
  __builtin_amdgcn_global_load_lds(
      (__attribute__((address_space(1))) void*)g,
      (__attribute__((address_space(3))) void*)l, 16, 0, 0);
}

// ---------------- fp32 -> bf16 convert ----------------
__global__ __launch_bounds__(256) void k_cvt(const float* __restrict__ in,
                                             unsigned short* __restrict__ out, int n4) {
  int i = blockIdx.x * 256 + threadIdx.x;
  if (i >= n4) return;
  float4 v = ((const float4*)in)[i];
  ushort4 o;
  o.x = f2bf(v.x); o.y = f2bf(v.y); o.z = f2bf(v.z); o.w = f2bf(v.w);
  ((ushort4*)out)[i] = o;
}

// ---------------- GEMM 256x256, BK=32, 4-deep LDS pipeline, counted vmcnt ---
// C[m][n] = sum_k A[m][k] * Bt[n][k].  512 thr = 8 waves (2M x 4N).
// LDS granule-rotation swizzle: LDS[r][slot g] holds global granule (g - (r>>1))&3.
template <int OUT_BF16>
__global__ __launch_bounds__(512, 1) void k_gemm256(const unsigned short* __restrict__ A,
                                                    const unsigned short* __restrict__ Bt,
                                                    void* __restrict__ Cout,
                                                    int M, int N, int K) {
  __shared__ __align__(16) unsigned short As[4][256 * 32];
  __shared__ __align__(16) unsigned short Bs[4][256 * 32];
  const int t = threadIdx.x, lane = t & 63;
  const int wid = t >> 6, wm = wid >> 2, wn = wid & 3;
  const int fr = lane & 15, kq = lane >> 4;
  // XCD-aware swizzle (nwg % 8 == 0 for both call sites)
  const int nwg = gridDim.x * gridDim.y;
  int lin = blockIdx.y * gridDim.x + blockIdx.x;
  lin = (lin & 7) * (nwg >> 3) + (lin >> 3);
  const int bx = lin % gridDim.x, by = lin / gridDim.x;
  const int row0 = by * 256, col0 = bx * 256;
  const int NT = K >> 5;

  // staging source indices: issue i covers LDS bytes (i*512+t)*16
  int srow[2], sgg[2];
#pragma unroll
  for (int i = 0; i < 2; ++i) {
    const int off = (i * 512 + t) * 16;
    srow[i] = off >> 6;                                // 64 B per row
    sgg[i] = (((off >> 4) & 3) - (srow[i] >> 1)) & 3;  // global granule for this slot
  }

#define STAGE(KT)                                                              \
  do {                                                                         \
    const int buf_ = (KT) & 3;                                                 \
    const int k0_ = (KT) * 32;                                                 \
    _Pragma("unroll") for (int i = 0; i < 2; ++i) {                            \
      gload16(A + (size_t)(row0 + srow[i]) * K + k0_ + sgg[i] * 8,             \
              (char*)As[buf_] + (i * 512 + wid * 64) * 16);                    \
      gload16(Bt + (size_t)(col0 + srow[i]) * K + k0_ + sgg[i] * 8,            \
              (char*)Bs[buf_] + (i * 512 + wid * 64) * 16);                    \
    }                                                                          \
  } while (0)

  f32x4 acc[8][4];
#pragma unroll
  for (int m = 0; m < 8; ++m)
#pragma unroll
    for (int n = 0; n < 4; ++n) acc[m][n] = f32x4{0.f, 0.f, 0.f, 0.f};

  STAGE(0); STAGE(1); STAGE(2);

  for (int kt = 0; kt < NT; ++kt) {
    // own stage(kt) retired: newer outstanding = stage(kt+1), stage(kt+2) = 8 instrs
    if (kt + 2 < NT)      asm volatile("s_waitcnt vmcnt(8)" ::: "memory");
    else if (kt + 1 < NT) asm volatile("s_waitcnt vmcnt(4)" ::: "memory");
    else                  asm volatile("s_waitcnt vmcnt(0)" ::: "memory");
    __builtin_amdgcn_s_barrier();  // all waves: kt landed; all kt-1 reads drained
    if (kt + 3 < NT) STAGE(kt + 3);

    const int buf = kt & 3;
    bf16x8 af[8], bfr[4];
#pragma unroll
    for (int m = 0; m < 8; ++m) {
      const int row = wm * 128 + m * 16 + fr;
      af[m] = *(const bf16x8*)((const char*)As[buf] + row * 64 +
                               (((kq + (row >> 1)) & 3) << 4));
    }
#pragma unroll
    for (int n = 0; n < 4; ++n) {
      const int row = wn * 64 + n * 16 + fr;
      bfr[n] = *(const bf16x8*)((const char*)Bs[buf] + row * 64 +
                                (((kq + (row >> 1)) & 3) << 4));
    }
    __builtin_amdgcn_s_setprio(1);
#pragma unroll
    for (int m = 0; m < 8; ++m)
#pragma unroll
      for (int n = 0; n < 4; ++n)
        acc[m][n] = __builtin_amdgcn_mfma_f32_16x16x32_bf16(af[m], bfr[n], acc[m][n], 0, 0, 0);
    __builtin_amdgcn_s_setprio(0);
  }
#undef STAGE

  const int rsub = kq * 4;
#pragma unroll
  for (int m = 0; m < 8; ++m)
#pragma unroll
    for (int n = 0; n < 4; ++n)
#pragma unroll
      for (int r = 0; r < 4; ++r) {
        const size_t row = (size_t)row0 + wm * 128 + m * 16 + rsub + r;
        const size_t col = (size_t)col0 + wn * 64 + n * 16 + fr;
        if (OUT_BF16)
          ((unsigned short*)Cout)[row * N + col] = f2bf(acc[m][n][r]);
        else
          ((float*)Cout)[row * N + col] = acc[m][n][r];
      }
}

// ---------------- RoPE + head split (qkv bf16 -> Q/K bf16; V skipped) ------
__global__ __launch_bounds__(256) void k_rope(const unsigned short* __restrict__ qkv,
                                              const float* __restrict__ fcos,
                                              const float* __restrict__ fsin,
                                              unsigned short* __restrict__ Qb,
                                              unsigned short* __restrict__ Kb) {
  const int idx = blockIdx.x * 256 + threadIdx.x;  // < 4096*768
  if (idx >= 4096 * 768) return;
  const int bt = idx / 768;
  const int oc = idx - bt * 768;
  const int o0 = oc * 8;
  const int g = o0 / 768;
  const int rem = o0 - g * 768;
  const int slot = rem >> 7;
  const int d0 = rem & 127;
  if (slot == 5) return;  // V handled by k_vtrans
  const int b = bt >> 10, tt = bt & 1023;

  uint4 raw = *(const uint4*)&qkv[(size_t)bt * 6144 + o0];
  unsigned short us[8] = {
      (unsigned short)(raw.x & 0xffff), (unsigned short)(raw.x >> 16),
      (unsigned short)(raw.y & 0xffff), (unsigned short)(raw.y >> 16),
      (unsigned short)(raw.z & 0xffff), (unsigned short)(raw.z >> 16),
      (unsigned short)(raw.w & 0xffff), (unsigned short)(raw.w >> 16)};

  float4 c = *(const float4*)&fcos[tt * 64 + (d0 >> 1)];
  float4 s = *(const float4*)&fsin[tt * 64 + (d0 >> 1)];
  const float sc = (slot < 4) ? 0.08838834764831845f : 1.0f;  // 1/sqrt(128) folded into Q
  float cj[4] = {c.x, c.y, c.z, c.w};
  float sj[4] = {s.x, s.y, s.z, s.w};
  unsigned short os[8];
#pragma unroll
  for (int j = 0; j < 4; ++j) {
    float x0 = bf2f(us[2 * j]), x1 = bf2f(us[2 * j + 1]);
    os[2 * j] = f2bf((x0 * cj[j] - x1 * sj[j]) * sc);
    os[2 * j + 1] = f2bf((x0 * sj[j] + x1 * cj[j]) * sc);
  }
  if (slot < 4) {
    const int h = g * 4 + slot;
    *(uint4*)&Qb[((size_t)(b * 32 + h) * 1024 + tt) * 128 + d0] = pack8(os);
  } else {
    *(uint4*)&Kb[((size_t)(b * 8 + g) * 1024 + tt) * 128 + d0] = pack8(os);
  }
}

// ---------------- V transpose: QKVB -> VT[bg][d=128][t=1024] ----------------
__global__ __launch_bounds__(256) void k_vtrans(const unsigned short* __restrict__ qkv,
                                                unsigned short* __restrict__ VT) {
  const int t = threadIdx.x;
  const int tt0 = blockIdx.x * 128;
  const int bg = blockIdx.y;
  const int b = bg >> 3, g = bg & 7;
  const int tj = t & 15;   // d-block (fast lane index -> coalesced reads)
  const int ti = t >> 4;   // t-block
  union U4 { uint4 v; unsigned int u[4]; };
  U4 in[8], out[8];
  const unsigned short* src =
      qkv + (size_t)(b * 1024 + tt0 + ti * 8) * 6144 + g * 768 + 640 + tj * 8;
#pragma unroll
  for (int r = 0; r < 8; ++r) in[r].v = *(const uint4*)(src + (size_t)r * 6144);
#pragma unroll
  for (int c = 0; c < 8; ++c) {
    const unsigned int sel = (c & 1) ? 0x07060302u : 0x05040100u;
    const int dw = c >> 1;
#pragma unroll
    for (int w = 0; w < 4; ++w)
      out[c].u[w] = __builtin_amdgcn_perm(in[2 * w + 1].u[dw], in[2 * w].u[dw], sel);
  }
  unsigned short* dst = VT + (size_t)bg * 131072 + (size_t)(tj * 8) * 1024 + tt0 + ti * 8;
#pragma unroll
  for (int c = 0; c < 8; ++c) *(uint4*)(dst + (size_t)c * 1024) = out[c].v;
}

// ---------------- causal GQA flash attention ----------------
__global__ __launch_bounds__(256) void k_attn(const unsigned short* __restrict__ Qb,
                                              const unsigned short* __restrict__ Kb,
                                              const unsigned short* __restrict__ VT,
                                              unsigned short* __restrict__ AO) {
  __shared__ __align__(16) unsigned short Ks[64 * 128];   // [kv][d], 256B rows, XOR-swz
  __shared__ __align__(16) unsigned short Vt[128 * 64];   // [d][kv], 128B rows, XOR-swz
  __shared__ __align__(16) unsigned short Ps[4 * 16 * 64]; // per-wave [q16][kv64], XOR-swz
  const int t = threadIdx.x, lane = t & 63, wv = t >> 6;
  const int bh = blockIdx.y;
  const int b = bh >> 5, h = bh & 31, g = h >> 2;
  const int qi = blockIdx.x;
  const int q0 = qi * 64;
  const int fr = lane & 15, kq = lane >> 4;
  const size_t kvbase = (size_t)(b * 8 + g) * (1024 * 128);
  const size_t vtbase = (size_t)(b * 8 + g) * (128 * 1024);

  bf16x8 qf[4];
  {
    const unsigned short* Qp = Qb + ((size_t)(b * 32 + h) * 1024 + q0 + wv * 16 + fr) * 128;
#pragma unroll
    for (int ks = 0; ks < 4; ++ks) qf[ks] = *(const bf16x8*)&Qp[ks * 32 + kq * 8];
  }
  float mrow[4] = {-1e30f, -1e30f, -1e30f, -1e30f};
  float lrow[4] = {0.f, 0.f, 0.f, 0.f};
  f32x4 of[8];
#pragma unroll
  for (int n = 0; n < 8; ++n) of[n] = f32x4{0.f, 0.f, 0.f, 0.f};

  for (int kt = 0; kt <= qi; ++kt) {
    const int kv0 = kt * 64;
#pragma unroll
    for (int it = 0; it < 4; ++it) {
      const int off = it * 4096 + wv * 1024 + lane * 16;
      {
        const int r = off >> 8, cb = off & 255;
        const int scb = cb ^ ((r & 7) << 4);
        gload16(Kb + kvbase + (size_t)(kv0 + r) * 128 + (scb >> 1),
                (char*)Ks + it * 4096 + wv * 1024);
      }
      {
        const int rd = off >> 7, cb = off & 127;
        const int scb = cb ^ ((rd & 7) << 4);
        gload16(VT + vtbase + (size_t)rd * 1024 + kv0 + (scb >> 1),
                (char*)Vt + it * 4096 + wv * 1024);
      }
    }
    __syncthreads();

    // S = Q K^T : 16q x 64kv per wave
    f32x4 sacc[4];
#pragma unroll
    for (int n = 0; n < 4; ++n) sacc[n] = f32x4{0.f, 0.f, 0.f, 0.f};
#pragma unroll
    for (int n = 0; n < 4; ++n) {
      const int row = n * 16 + fr;
      const int sw = (row & 7) << 4;
#pragma unroll
      for (int ks = 0; ks < 4; ++ks) {
        bf16x8 kf = *(const bf16x8*)((const char*)Ks + row * 256 + ((ks * 64 + kq * 16) ^ sw));
        sacc[n] = __builtin_amdgcn_mfma_f32_16x16x32_bf16(qf[ks], kf, sacc[n], 0, 0, 0);
      }
    }

    // online softmax; rows: q = kq*4+rg, cols: kv = n*16+fr
#pragma unroll
    for (int rg = 0; rg < 4; ++rg) {
      const int qrow = q0 + wv * 16 + kq * 4 + rg;
      float s[4];
#pragma unroll
      for (int n = 0; n < 4; ++n) {
        s[n] = sacc[n][rg];
        if (kv0 + n * 16 + fr > qrow) s[n] = -1e30f;
      }
      float mx = fmaxf(fmaxf(s[0], s[1]), fmaxf(s[2], s[3]));
#pragma unroll
      for (int o = 1; o < 16; o <<= 1) mx = fmaxf(mx, __shfl_xor(mx, o));
      const float mnew = fmaxf(mrow[rg], mx);
      float p[4];
#pragma unroll
      for (int n = 0; n < 4; ++n) p[n] = __expf(s[n] - mnew);
      float sum = (p[0] + p[1]) + (p[2] + p[3]);
#pragma unroll
      for (int o = 1; o < 16; o <<= 1) sum += __shfl_xor(sum, o);
      const float fac = __expf(mrow[rg] - mnew);
      lrow[rg] = lrow[rg] * fac + sum;
      mrow[rg] = mnew;
#pragma unroll
      for (int n = 0; n < 8; ++n) of[n][rg] *= fac;
      const int q = kq * 4 + rg;
      const int swp = (q & 7) << 4;
#pragma unroll
      for (int n = 0; n < 4; ++n)
        *(unsigned short*)((char*)Ps + wv * 2048 + q * 128 + ((2 * (n * 16 + fr)) ^ swp)) =
            f2bf(p[n]);
    }

    // PV: O += P[16x64] * V^T  (per-wave Ps, no barrier needed)
    bf16x8 pa[2];
#pragma unroll
    for (int kk = 0; kk < 2; ++kk)
      pa[kk] = *(const bf16x8*)((const char*)Ps + wv * 2048 + fr * 128 +
                                ((kk * 64 + kq * 16) ^ ((fr & 7) << 4)));
#pragma unroll
    for (int n = 0; n < 8; ++n) {
      const int row = n * 16 + fr;
      const int sw = (row & 7) << 4;
#pragma unroll
      for (int kk = 0; kk < 2; ++kk) {
        bf16x8 vf = *(const bf16x8*)((const char*)Vt + row * 128 + ((kk * 64 + kq * 16) ^ sw));
        of[n] = __builtin_amdgcn_mfma_f32_16x16x32_bf16(pa[kk], vf, of[n], 0, 0, 0);
      }
    }
    __syncthreads();
  }

  float inv[4];
#pragma unroll
  for (int rg = 0; rg < 4; ++rg) inv[rg] = 1.0f / lrow[rg];
#pragma unroll
  for (int n = 0; n < 8; ++n)
#pragma unroll
    for (int rg = 0; rg < 4; ++rg) {
      const size_t row = (size_t)b * 1024 + q0 + wv * 16 + kq * 4 + rg;
      const size_t col = (size_t)h * 128 + n * 16 + fr;
      AO[row * 4096 + col] = f2bf(of[n][rg] * inv[rg]);
    }
}

// ---------------- launch ----------------
extern "C" void kernel_launch(void* const* d_in, const int* in_sizes, int n_in,
                              void* d_out, int out_size, void* d_ws, size_t ws_size,
                              hipStream_t stream) {
  const float* x = (const float*)d_in[0];
  const float* w_qkv = (const float*)d_in[1];
  const float* w_proj = (const float*)d_in[2];
  const float* fcos = (const float*)d_in[3];
  const float* fsin = (const float*)d_in[4];
  float* out = (float*)d_out;

  char* ws = (char*)d_ws;
  unsigned short* XB    = (unsigned short*)(ws + 0);          // x bf16
  unsigned short* WQKVB = (unsigned short*)(ws + 33554432);   // w_qkv bf16
  unsigned short* QKVB  = (unsigned short*)(ws + 83886080);   // qkv bf16
  unsigned short* QB    = (unsigned short*)(ws + 134217728);
  unsigned short* KB    = (unsigned short*)(ws + 167772160);
  unsigned short* VTB   = (unsigned short*)(ws + 176160768);  // V^T [bg][128][1024]
  unsigned short* WPROJB = XB;    // reuse x slot after GEMM1
  unsigned short* AOB    = QKVB;  // reuse qkv slot (V read via VTB)

  k_cvt<<<16384, 256, 0, stream>>>(x, XB, 4194304);
  k_cvt<<<24576, 256, 0, stream>>>(w_qkv, WQKVB, 6291456);
  k_gemm256<1><<<dim3(24, 16), 512, 0, stream>>>(XB, WQKVB, QKVB, 4096, 6144, 4096);
  k_cvt<<<16384, 256, 0, stream>>>(w_proj, WPROJB, 4194304);
  k_rope<<<12288, 256, 0, stream>>>(QKVB, fcos, fsin, QB, KB);
  k_vtrans<<<dim3(8, 32), 256, 0, stream>>>(QKVB, VTB);
  k_attn<<<dim3(16, 128), 256, 0, stream>>>(QB, KB, VTB, AOB);
  k_gemm256<0><<<dim3(16, 16), 512, 0, stream>>>(AOB, WPROJB, out, 4096, 4096, 4096);
}